// Round 1
// baseline (135.587 us; speedup 1.0000x reference)
//
#include <hip/hip_runtime.h>
#include <math.h>

#define N_ROWS 4096
#define K_DIM  2048
#define C_DIM  4096

__device__ __forceinline__ float4 ld4(const float* p) {
    return *reinterpret_cast<const float4*>(p);
}

// Reduce NV per-thread partials to totals on thread 0. lds must be [NV][8].
template<int NV>
__device__ __forceinline__ void block_reduce(float* vals, float (*lds)[8]) {
    int lane = threadIdx.x & 63;
    int wv   = threadIdx.x >> 6;
#pragma unroll
    for (int i = 0; i < NV; ++i) {
        float val = vals[i];
#pragma unroll
        for (int off = 32; off > 0; off >>= 1)
            val += __shfl_down(val, off, 64);
        if (lane == 0) lds[i][wv] = val;
    }
    __syncthreads();
    if (threadIdx.x == 0) {
        int nw = blockDim.x >> 6;
#pragma unroll
        for (int i = 0; i < NV; ++i) {
            float s = 0.f;
            for (int w = 0; w < nw; ++w) s += lds[i][w];
            vals[i] = s;
        }
    }
}

// Kernel 1: p_a[k] = cov_kernel[k,:] . w_a ; p_b[k] = cov_kernel[k,:] . w_b
// Extra block (row == K_DIM) computes ca = cov_bias.w_a, cb = cov_bias.w_b.
__global__ __launch_bounds__(256) void k_proj(const float* __restrict__ covk,
                                              const float* __restrict__ covb,
                                              const float* __restrict__ rho,
                                              float* __restrict__ pa,
                                              float* __restrict__ pb,
                                              float* __restrict__ cab) {
    __shared__ float lds[2][8];
    int row = blockIdx.x;
    const float* src = (row < K_DIM) ? covk + (size_t)row * C_DIM : covb;
    const float* wa = rho;
    const float* wb = rho + C_DIM;
    float s[2] = {0.f, 0.f};
    int t = threadIdx.x;
#pragma unroll
    for (int it = 0; it < 4; ++it) {
        int j = (it * 256 + t) * 4;
        float4 c = ld4(src + j);
        float4 a = ld4(wa + j);
        float4 b = ld4(wb + j);
        s[0] += c.x * a.x + c.y * a.y + c.z * a.z + c.w * a.w;
        s[1] += c.x * b.x + c.y * b.y + c.z * b.z + c.w * b.w;
    }
    block_reduce<2>(s, lds);
    if (t == 0) {
        if (row < K_DIM) { pa[row] = s[0]; pb[row] = s[1]; }
        else             { cab[0] = s[0]; cab[1] = s[1]; }
    }
}

// Kernel 2: one block per row i of x. Four fused dot products over x[i,:]:
//   u[i] = x[i].p_a + ca,  v[i] = x[i].p_b + cb,
//   out_mu[i] = x[i].mu_kernel + mu_bias,
//   d[i] = softplus(x[i].var_kernel + var_bias) + 1e-8.
__global__ __launch_bounds__(256) void k_xdots(const float* __restrict__ x,
                                               const float* __restrict__ pa,
                                               const float* __restrict__ pb,
                                               const float* __restrict__ muk,
                                               const float* __restrict__ vark,
                                               const float* __restrict__ cab,
                                               const float* __restrict__ mub,
                                               const float* __restrict__ varb,
                                               float* __restrict__ u,
                                               float* __restrict__ v,
                                               float* __restrict__ dd,
                                               float* __restrict__ out_mu) {
    __shared__ float lds[4][8];
    int i = blockIdx.x;
    const float* xr = x + (size_t)i * K_DIM;
    float s[4] = {0.f, 0.f, 0.f, 0.f};
    int t = threadIdx.x;
#pragma unroll
    for (int it = 0; it < 2; ++it) {
        int j = (it * 256 + t) * 4;
        float4 xv = ld4(xr + j);
        float4 a  = ld4(pa + j);
        float4 b  = ld4(pb + j);
        float4 m  = ld4(muk + j);
        float4 w  = ld4(vark + j);
        s[0] += xv.x * a.x + xv.y * a.y + xv.z * a.z + xv.w * a.w;
        s[1] += xv.x * b.x + xv.y * b.y + xv.z * b.z + xv.w * b.w;
        s[2] += xv.x * m.x + xv.y * m.y + xv.z * m.z + xv.w * m.w;
        s[3] += xv.x * w.x + xv.y * w.y + xv.z * w.z + xv.w * w.w;
    }
    block_reduce<4>(s, lds);
    if (t == 0) {
        u[i] = s[0] + cab[0];
        v[i] = s[1] + cab[1];
        out_mu[i] = s[2] + mub[0];
        float tt = s[3] + varb[0];
        float sp = (tt > 20.f) ? tt : log1pf(expf(tt));
        dd[i] = sp + 1e-8f;
    }
}

// Kernel 3: inclusive prefix sums over v: S1[m] = sum_{k<=m} v_k, S2[m] = sum v_k^2.
// Single block, 1024 threads, 4 elems/thread + Hillis-Steele block scan.
__global__ __launch_bounds__(1024) void k_scan(const float* __restrict__ v,
                                               float* __restrict__ S1,
                                               float* __restrict__ S2) {
    __shared__ float l1[1024];
    __shared__ float l2[1024];
    int t = threadIdx.x;
    float4 vv = ld4(v + t * 4);
    float a0 = vv.x;
    float a1 = a0 + vv.y;
    float a2 = a1 + vv.z;
    float a3 = a2 + vv.w;
    float q0 = vv.x * vv.x;
    float q1 = q0 + vv.y * vv.y;
    float q2 = q1 + vv.z * vv.z;
    float q3 = q2 + vv.w * vv.w;
    l1[t] = a3;
    l2[t] = q3;
    __syncthreads();
    for (int off = 1; off < 1024; off <<= 1) {
        float x1 = (t >= off) ? l1[t - off] : 0.f;
        float x2 = (t >= off) ? l2[t - off] : 0.f;
        __syncthreads();
        l1[t] += x1;
        l2[t] += x2;
        __syncthreads();
    }
    float base1 = (t > 0) ? l1[t - 1] : 0.f;
    float base2 = (t > 0) ? l2[t - 1] : 0.f;
    float4 o1 = make_float4(base1 + a0, base1 + a1, base1 + a2, base1 + a3);
    float4 o2 = make_float4(base2 + q0, base2 + q1, base2 + q2, base2 + q3);
    *reinterpret_cast<float4*>(S1 + t * 4) = o1;
    *reinterpret_cast<float4*>(S2 + t * 4) = o2;
}

// Kernel 4: fill output_cov[i,j] = (m+1)*u_i*u_j + (u_i+u_j)*S1[m] + S2[m],
// m = min(i,j); diagonal = d[i]. 4 consecutive j per thread, float4 store.
__global__ __launch_bounds__(256) void k_cov(const float* __restrict__ u,
                                             const float* __restrict__ S1,
                                             const float* __restrict__ S2,
                                             const float* __restrict__ dd,
                                             float* __restrict__ out) {
    int i  = blockIdx.y;
    int j0 = (blockIdx.x * 256 + threadIdx.x) * 4;
    float ui = u[i];
    float4 uj = ld4(u + j0);
    float4 r;
    if (j0 + 3 < i) {
        // fully below diagonal: m = j
        float4 s1 = ld4(S1 + j0);
        float4 s2 = ld4(S2 + j0);
        r.x = (float)(j0 + 1) * ui * uj.x + (ui + uj.x) * s1.x + s2.x;
        r.y = (float)(j0 + 2) * ui * uj.y + (ui + uj.y) * s1.y + s2.y;
        r.z = (float)(j0 + 3) * ui * uj.z + (ui + uj.z) * s1.z + s2.z;
        r.w = (float)(j0 + 4) * ui * uj.w + (ui + uj.w) * s1.w + s2.w;
    } else if (j0 > i) {
        // fully above diagonal: m = i
        float mi = (float)(i + 1);
        float s1i = S1[i], s2i = S2[i];
        r.x = mi * ui * uj.x + (ui + uj.x) * s1i + s2i;
        r.y = mi * ui * uj.y + (ui + uj.y) * s1i + s2i;
        r.z = mi * ui * uj.z + (ui + uj.z) * s1i + s2i;
        r.w = mi * ui * uj.w + (ui + uj.w) * s1i + s2i;
    } else {
        // straddles the diagonal
        float s1i = S1[i], s2i = S2[i];
        float di = dd[i];
        float uu[4] = {uj.x, uj.y, uj.z, uj.w};
        float rr[4];
#pragma unroll
        for (int e = 0; e < 4; ++e) {
            int j = j0 + e;
            if (j < i)
                rr[e] = (float)(j + 1) * ui * uu[e] + (ui + uu[e]) * S1[j] + S2[j];
            else if (j == i)
                rr[e] = di;
            else
                rr[e] = (float)(i + 1) * ui * uu[e] + (ui + uu[e]) * s1i + s2i;
        }
        r = make_float4(rr[0], rr[1], rr[2], rr[3]);
    }
    *reinterpret_cast<float4*>(out + (size_t)i * C_DIM + j0) = r;
}

extern "C" void kernel_launch(void* const* d_in, const int* in_sizes, int n_in,
                              void* d_out, int out_size, void* d_ws, size_t ws_size,
                              hipStream_t stream) {
    const float* x    = (const float*)d_in[0];
    const float* muk  = (const float*)d_in[1];
    const float* mub  = (const float*)d_in[2];
    const float* covk = (const float*)d_in[3];
    const float* covb = (const float*)d_in[4];
    const float* vark = (const float*)d_in[5];
    const float* varb = (const float*)d_in[6];
    const float* rho  = (const float*)d_in[7];

    float* out_mu  = (float*)d_out;           // (4096,1) flattened
    float* out_cov = (float*)d_out + N_ROWS;  // (4096,4096)

    float* ws  = (float*)d_ws;
    float* pa  = ws;             // 2048
    float* pb  = pa + K_DIM;     // 2048
    float* cab = pb + K_DIM;     // 2 (padded to 64 for alignment)
    float* u   = cab + 64;       // 4096
    float* v   = u + C_DIM;      // 4096
    float* dd  = v + C_DIM;      // 4096
    float* S1  = dd + C_DIM;     // 4096
    float* S2  = S1 + C_DIM;     // 4096  (total ~100 KB)

    hipLaunchKernelGGL(k_proj, dim3(K_DIM + 1), dim3(256), 0, stream,
                       covk, covb, rho, pa, pb, cab);
    hipLaunchKernelGGL(k_xdots, dim3(N_ROWS), dim3(256), 0, stream,
                       x, pa, pb, muk, vark, cab, mub, varb, u, v, dd, out_mu);
    hipLaunchKernelGGL(k_scan, dim3(1), dim3(1024), 0, stream, v, S1, S2);
    hipLaunchKernelGGL(k_cov, dim3(C_DIM / 1024, N_ROWS), dim3(256), 0, stream,
                       u, S1, S2, dd, out_cov);
}